// Round 1
// baseline (107.290 us; speedup 1.0000x reference)
//
#include <hip/hip_runtime.h>
#include <math.h>

#define NROWS 4096
#define NCLS  32000
#define VEC_PER_ROW (NCLS / 4)   // 8000 float4s per row
#define BLK 1024
#define EPSF 1e-6f

// ln(4095/4096), precomputed in double precision
#define LNBETA (-2.4417042724800387e-4f)
// (1 - beta) = 1/4096 exactly
#define WNUM 2.44140625e-4f

__device__ __forceinline__ float max4(float4 v) {
    return fmaxf(fmaxf(v.x, v.y), fmaxf(v.z, v.w));
}
__device__ __forceinline__ float sum4(float4 v) {
    return (v.x + v.y) + (v.z + v.w);
}

// One row per block. 1024 threads * 8 float4 = 32768 >= 32000 elements.
__global__ __launch_bounds__(BLK) void focal_kernel(const float* __restrict__ pred,
                                                    float* __restrict__ focal_out)
{
    const int row = blockIdx.x;
    const int tid = threadIdx.x;
    const float4* rp = reinterpret_cast<const float4*>(pred) + (size_t)row * VEC_PER_ROW;

    float4 x[8];
#pragma unroll
    for (int i = 0; i < 7; ++i) x[i] = rp[tid + i * BLK];
    const bool lv = (tid + 7 * BLK) < VEC_PER_ROW;   // tid < 832
    if (lv) x[7] = rp[tid + 7 * BLK];
    else    x[7] = make_float4(-1e30f, -1e30f, -1e30f, -1e30f);

    // ---- pass A: per-thread max + sum ----
    float m = -1e30f, s1 = 0.0f;
#pragma unroll
    for (int i = 0; i < 7; ++i) { m = fmaxf(m, max4(x[i])); s1 += sum4(x[i]); }
    m = fmaxf(m, max4(x[7]));
    if (lv) s1 += sum4(x[7]);

    // ---- block reduce (max, sum) ----
    __shared__ float sm[16], ss[16];
#pragma unroll
    for (int off = 32; off > 0; off >>= 1) {
        m  = fmaxf(m, __shfl_xor(m, off));
        s1 += __shfl_xor(s1, off);
    }
    const int wid = tid >> 6;
    const int lane = tid & 63;
    if (lane == 0) { sm[wid] = m; ss[wid] = s1; }
    __syncthreads();
    if (tid < 64) {
        float mm = (tid < 16) ? sm[tid] : -1e30f;
        float s  = (tid < 16) ? ss[tid] : 0.0f;
#pragma unroll
        for (int off = 8; off > 0; off >>= 1) {
            mm = fmaxf(mm, __shfl_xor(mm, off));
            s += __shfl_xor(s, off);
        }
        if (tid == 0) { sm[0] = mm; ss[0] = s; }
    }
    __syncthreads();
    const float M  = sm[0];
    const float S1 = ss[0];

    // ---- pass B (registers only): Z, A=Σe^t·t, Z2=Σe^2t, A2=Σe^2t·t ----
    float Z = 0.f, A = 0.f, Z2 = 0.f, A2 = 0.f;
#pragma unroll
    for (int i = 0; i < 8; ++i) {
        float vals[4] = {x[i].x, x[i].y, x[i].z, x[i].w};
#pragma unroll
        for (int j = 0; j < 4; ++j) {
            float t = vals[j] - M;                       // masked lanes: t ~ -1e30
            float e = exp2f(t * 1.44269504088896340736f); // e^t ; masked -> 0
            Z += e;
            A = fmaf(e, t, A);                            // 0 * -1e30 = 0, safe
            float e2 = e * e;
            Z2 += e2;
            A2 = fmaf(e2, t, A2);
        }
    }

    // ---- block reduce 4 accumulators ----
    __shared__ float r0[16], r1[16], r2[16], r3[16];
#pragma unroll
    for (int off = 32; off > 0; off >>= 1) {
        Z  += __shfl_xor(Z,  off);
        A  += __shfl_xor(A,  off);
        Z2 += __shfl_xor(Z2, off);
        A2 += __shfl_xor(A2, off);
    }
    if (lane == 0) { r0[wid] = Z; r1[wid] = A; r2[wid] = Z2; r3[wid] = A2; }
    __syncthreads();
    if (tid < 64) {
        float a = (tid < 16) ? r0[tid] : 0.f;
        float b = (tid < 16) ? r1[tid] : 0.f;
        float c = (tid < 16) ? r2[tid] : 0.f;
        float d = (tid < 16) ? r3[tid] : 0.f;
#pragma unroll
        for (int off = 8; off > 0; off >>= 1) {
            a += __shfl_xor(a, off);
            b += __shfl_xor(b, off);
            c += __shfl_xor(c, off);
            d += __shfl_xor(d, off);
        }
        if (tid == 0) {
            float lnZ  = log2f(a) * 0.69314718055994530942f;
            float invZ = 1.0f / a;
            float T = S1 - (float)NCLS * M;
            // focal = Σ(1-p)^2 * logp, expanded in (t, lnZ)
            float focal = (T - (float)NCLS * lnZ)
                        - 2.0f * (b * invZ - lnZ)
                        + (d - lnZ * c) * (invZ * invZ);
            focal_out[row] = focal;
        }
    }
}

__global__ void count_kernel(const int* __restrict__ target, int* __restrict__ counts)
{
    int b = blockIdx.x * blockDim.x + threadIdx.x;
    if (b < NROWS) atomicAdd(&counts[target[b]], 1);
}

__global__ __launch_bounds__(1024) void finalize_kernel(const int* __restrict__ target,
                                                        const float* __restrict__ focal,
                                                        const int* __restrict__ counts,
                                                        float* __restrict__ out)
{
    const int tid = threadIdx.x;
    double local = 0.0;
    for (int b = tid; b < NROWS; b += 1024) {
        int t = target[b];
        int n = counts[t];               // n >= 1 for present classes
        float u = (float)n * LNBETA;     // u = n * ln(beta), small negative
        float denom;
        if (u > -0.25f) {
            // 1 - beta^n = -expm1(u) ~= -(u + u^2/2 + u^3/6 + u^4/24)
            denom = -(u * (1.f + u * (0.5f + u * (0.16666667f + u * 0.041666667f))));
        } else {
            denom = 1.f - __expf(u);
        }
        float w = WNUM / (denom + EPSF);
        local += (double)(w * (float)t * focal[b]);
    }

    // block reduce (double)
    __shared__ double rd[16];
#pragma unroll
    for (int off = 32; off > 0; off >>= 1) local += __shfl_xor(local, off);
    const int wid = tid >> 6, lane = tid & 63;
    if (lane == 0) rd[wid] = local;
    __syncthreads();
    if (tid < 64) {
        double v = (tid < 16) ? rd[tid] : 0.0;
#pragma unroll
        for (int off = 8; off > 0; off >>= 1) v += __shfl_xor(v, off);
        if (tid == 0) out[0] = (float)(v * (-1.0 / (double)NROWS));
    }
}

extern "C" void kernel_launch(void* const* d_in, const int* in_sizes, int n_in,
                              void* d_out, int out_size, void* d_ws, size_t ws_size,
                              hipStream_t stream)
{
    const float* pred  = (const float*)d_in[0];
    const int* target  = (const int*)d_in[1];
    float* out         = (float*)d_out;

    float* focal = (float*)d_ws;                                  // 4096 floats
    int* counts  = (int*)((char*)d_ws + NROWS * sizeof(float));   // 32000 ints

    hipMemsetAsync(counts, 0, NCLS * sizeof(int), stream);
    focal_kernel<<<NROWS, BLK, 0, stream>>>(pred, focal);
    count_kernel<<<(NROWS + 255) / 256, 256, 0, stream>>>(target, counts);
    finalize_kernel<<<1, 1024, 0, stream>>>(target, focal, counts, out);
}

// Round 2
// 98.330 us; speedup vs baseline: 1.0911x; 1.0911x over previous
//
#include <hip/hip_runtime.h>
#include <math.h>

#define NROWS 4096
#define NCLS  32000
#define VEC_PER_ROW (NCLS / 4)   // 8000 float4s per row
#define BLK 512
#define NV  16                   // float4 per thread: 512*16 = 8192 >= 8000
#define TAIL (VEC_PER_ROW - (NV - 1) * BLK)   // 320
#define EPSF 1e-6f

// ln(4095/4096), precomputed in double precision
#define LNBETA (-2.4417042724800387e-4f)
// (1 - beta) = 1/4096 exactly
#define WNUM 2.44140625e-4f

__device__ __forceinline__ float max4(float4 v) {
    return fmaxf(fmaxf(v.x, v.y), fmaxf(v.z, v.w));
}
__device__ __forceinline__ float sum4(float4 v) {
    return (v.x + v.y) + (v.z + v.w);
}

// One row per block. 512 threads * 16 float4, last vec masked for tid >= 320.
// __launch_bounds__(512,4): cap VGPR at 128 -> 2 blocks/CU so one block's
// exp-phase overlaps the other's load-phase.
__global__ __launch_bounds__(BLK, 4) void focal_kernel(const float* __restrict__ pred,
                                                       float* __restrict__ focal_out)
{
    const int row = blockIdx.x;
    const int tid = threadIdx.x;
    const float4* rp = reinterpret_cast<const float4*>(pred) + (size_t)row * VEC_PER_ROW;

    float4 x[NV];
#pragma unroll
    for (int i = 0; i < NV - 1; ++i) x[i] = rp[tid + i * BLK];
    const bool lv = tid < TAIL;
    if (lv) x[NV - 1] = rp[tid + (NV - 1) * BLK];
    else    x[NV - 1] = make_float4(-1e30f, -1e30f, -1e30f, -1e30f);

    // ---- pass A: per-thread max + sum ----
    float m = -1e30f, s1 = 0.0f;
#pragma unroll
    for (int i = 0; i < NV - 1; ++i) { m = fmaxf(m, max4(x[i])); s1 += sum4(x[i]); }
    m = fmaxf(m, max4(x[NV - 1]));
    if (lv) s1 += sum4(x[NV - 1]);

    // ---- block reduce (max, sum): 8 waves ----
    __shared__ float sm[8], ss[8];
#pragma unroll
    for (int off = 32; off > 0; off >>= 1) {
        m  = fmaxf(m, __shfl_xor(m, off));
        s1 += __shfl_xor(s1, off);
    }
    const int wid  = tid >> 6;
    const int lane = tid & 63;
    if (lane == 0) { sm[wid] = m; ss[wid] = s1; }
    __syncthreads();
    if (tid < 64) {
        float mm = (tid < 8) ? sm[tid] : -1e30f;
        float s  = (tid < 8) ? ss[tid] : 0.0f;
#pragma unroll
        for (int off = 4; off > 0; off >>= 1) {
            mm = fmaxf(mm, __shfl_xor(mm, off));
            s += __shfl_xor(s, off);
        }
        if (tid == 0) { sm[0] = mm; ss[0] = s; }
    }
    __syncthreads();
    const float M  = sm[0];
    const float S1 = ss[0];

    // ---- pass B (registers only): Z, A=Σe^t·t, Z2=Σe^2t, A2=Σe^2t·t ----
    float Z = 0.f, A = 0.f, Z2 = 0.f, A2 = 0.f;
#pragma unroll
    for (int i = 0; i < NV; ++i) {
        float vals[4] = {x[i].x, x[i].y, x[i].z, x[i].w};
#pragma unroll
        for (int j = 0; j < 4; ++j) {
            float t = vals[j] - M;                        // masked lanes: t ~ -1e30 (finite)
            float e = exp2f(t * 1.44269504088896340736f); // e^t ; masked -> 0
            Z += e;
            A = fmaf(e, t, A);                            // fma(0, -1e30, A) = A, safe
            float e2 = e * e;
            Z2 += e2;
            A2 = fmaf(e2, t, A2);
        }
    }

    // ---- block reduce 4 accumulators ----
    __shared__ float r0[8], r1[8], r2[8], r3[8];
#pragma unroll
    for (int off = 32; off > 0; off >>= 1) {
        Z  += __shfl_xor(Z,  off);
        A  += __shfl_xor(A,  off);
        Z2 += __shfl_xor(Z2, off);
        A2 += __shfl_xor(A2, off);
    }
    if (lane == 0) { r0[wid] = Z; r1[wid] = A; r2[wid] = Z2; r3[wid] = A2; }
    __syncthreads();
    if (tid < 64) {
        float a = (tid < 8) ? r0[tid] : 0.f;
        float b = (tid < 8) ? r1[tid] : 0.f;
        float c = (tid < 8) ? r2[tid] : 0.f;
        float d = (tid < 8) ? r3[tid] : 0.f;
#pragma unroll
        for (int off = 4; off > 0; off >>= 1) {
            a += __shfl_xor(a, off);
            b += __shfl_xor(b, off);
            c += __shfl_xor(c, off);
            d += __shfl_xor(d, off);
        }
        if (tid == 0) {
            float lnZ  = log2f(a) * 0.69314718055994530942f;
            float invZ = 1.0f / a;
            float T = S1 - (float)NCLS * M;
            // focal = Σ(1-p)^2 * logp, expanded in (t, lnZ)
            float focal = (T - (float)NCLS * lnZ)
                        - 2.0f * (b * invZ - lnZ)
                        + (d - lnZ * c) * (invZ * invZ);
            focal_out[row] = focal;
        }
    }
}

// Fused count + finalize: packed 16-bit LDS histogram (counts <= 4096 fit u16),
// 16000 u32 words = 64 KB LDS. Removes memsetAsync + count_kernel dispatches.
__global__ __launch_bounds__(1024) void finalize_kernel(const int* __restrict__ target,
                                                        const float* __restrict__ focal,
                                                        float* __restrict__ out)
{
    __shared__ unsigned int cnt[NCLS / 2];   // 64000 B
    __shared__ double rd[16];
    const int tid = threadIdx.x;

    // zero histogram
    uint4* c4 = reinterpret_cast<uint4*>(cnt);
    for (int i = tid; i < NCLS / 8; i += 1024) c4[i] = make_uint4(0u, 0u, 0u, 0u);
    __syncthreads();

    // build histogram (packed 16-bit lanes; max count 4096 < 65536, no carry-out)
    for (int b = tid; b < NROWS; b += 1024) {
        int t = target[b];
        atomicAdd(&cnt[t >> 1], 1u << ((t & 1) * 16));
    }
    __syncthreads();

    double local = 0.0;
    for (int b = tid; b < NROWS; b += 1024) {
        int t = target[b];
        int n = (int)((cnt[t >> 1] >> ((t & 1) * 16)) & 0xffffu);  // n >= 1
        float u = (float)n * LNBETA;       // u = n * ln(beta), small negative
        float denom;
        if (u > -0.25f) {
            // 1 - beta^n = -expm1(u) ~= -(u + u^2/2 + u^3/6 + u^4/24)
            denom = -(u * (1.f + u * (0.5f + u * (0.16666667f + u * 0.041666667f))));
        } else {
            denom = 1.f - __expf(u);
        }
        float w = WNUM / (denom + EPSF);
        local += (double)(w * (float)t * focal[b]);
    }

    // block reduce (double)
#pragma unroll
    for (int off = 32; off > 0; off >>= 1) local += __shfl_xor(local, off);
    const int wid = tid >> 6, lane = tid & 63;
    if (lane == 0) rd[wid] = local;
    __syncthreads();
    if (tid < 64) {
        double v = (tid < 16) ? rd[tid] : 0.0;
#pragma unroll
        for (int off = 8; off > 0; off >>= 1) v += __shfl_xor(v, off);
        if (tid == 0) out[0] = (float)(v * (-1.0 / (double)NROWS));
    }
}

extern "C" void kernel_launch(void* const* d_in, const int* in_sizes, int n_in,
                              void* d_out, int out_size, void* d_ws, size_t ws_size,
                              hipStream_t stream)
{
    const float* pred  = (const float*)d_in[0];
    const int* target  = (const int*)d_in[1];
    float* out         = (float*)d_out;

    float* focal = (float*)d_ws;   // 4096 floats

    focal_kernel<<<NROWS, BLK, 0, stream>>>(pred, focal);
    finalize_kernel<<<1, 1024, 0, stream>>>(target, focal, out);
}